// Round 1
// baseline (5000.174 us; speedup 1.0000x reference)
//
#include <hip/hip_runtime.h>
#include <math.h>

#define V_ 20000
#define K_ 50
#define T_ 50
#define E_ 300
#define TH_ 800
#define EH_ 200
#define B_ 64

// ---- workspace layout (float offsets) ----
#define WS_SC      0        // [0]=kl_alpha [1]=kl_eta [2]=kl_theta_sum [3]=nll_sum
#define WS_ALPHAS  8        // 750000
#define WS_X0      750008   // 10000
#define WS_X1      760008   // 10000
#define WS_PRE     770008   // 40000
#define WS_ETAS    810008   // 2500
#define WS_H1      812508   // 51200
#define WS_H2      863708   // 51200
#define WS_THETA   914908   // 3200
#define WS_M       918108   // 2500
#define WS_S       920608   // 2500
#define WS_PM      923108   // 157*2500 = 392500
#define WS_PS      1315608  // 392500   -> total 1708108 floats (~6.8 MB)

#define SA 68     // LDS row stride (floats) for GEMM tiles: 16B-aligned, <=2-way bank conflicts
#define SNB 204   // LDS row stride for h1 gemm tiles

__device__ __forceinline__ float sigf(float x){ return 1.0f/(1.0f+expf(-x)); }

// ------------------------------------------------------------------
__global__ void k_zero(float* ws){
  int i = blockIdx.x*256 + threadIdx.x;
  if (i < 8) ws[WS_SC + i] = 0.f;
  else if (i < 8 + 10000) ws[WS_X0 + (i-8)] = 0.f;
  else if (i < 8 + 10000 + 51200) ws[WS_H1 + (i-10008)] = 0.f;
}

// ---- alphas = mu + eps*exp(0.5 ls); kl_alpha ----
__global__ void __launch_bounds__(256) k_alpha(const float* mu_q, const float* ls_q,
                                               const float* eps, float* ws){
  int bid = blockIdx.x; int t = bid / K_, k = bid % K_;
  int tid = threadIdx.x;
  const float log_delta = logf(0.005f);
  const float pvar = expf(log_delta) + 1e-6f;
  float kl = 0.f;
  for (int e = tid; e < E_; e += 256){
    float mu = mu_q[(k*T_ + t)*E_ + e];
    float ls = ls_q[(k*T_ + t)*E_ + e];
    float ep = eps[(t*K_ + k)*E_ + e];
    float al = mu + ep*expf(0.5f*ls);
    ws[WS_ALPHAS + (t*K_ + k)*E_ + e] = al;
    if (t == 0){
      kl += 0.5f*((expf(ls) + mu*mu)/(1.f + 1e-6f) - 1.f - ls);
    } else {
      float mup = mu_q[(k*T_ + (t-1))*E_ + e];
      float lsp = ls_q[(k*T_ + (t-1))*E_ + e];
      float epp = eps[((t-1)*K_ + k)*E_ + e];
      float ap  = mup + epp*expf(0.5f*lsp);
      float d = mu - ap;
      kl += 0.5f*((expf(ls) + d*d)/pvar - 1.f + log_delta - ls);
    }
  }
  __shared__ float red[256];
  red[tid] = kl; __syncthreads();
  for (int s = 128; s; s >>= 1){ if (tid < s) red[tid] += red[tid+s]; __syncthreads(); }
  if (tid == 0) atomicAdd(&ws[WS_SC + 0], red[0]);
}

// ---- x0[t,h] = rnn_inp[t,:] . eta_map_W[h,:]  (bias added later at stage) ----
__global__ void __launch_bounds__(256) k_eta_map(const float* rnn, const float* W, float* ws){
  // grid (10 vchunks, 25 htiles)
  int v0 = blockIdx.x * 2000;
  int h0 = blockIdx.y * 8;
  int tid = threadIdx.x;
  __shared__ float Wsh[8*2000];
  for (int idx = tid; idx < 16000; idx += 256){
    int hh = idx / 2000, v = idx % 2000;
    Wsh[idx] = W[(size_t)(h0+hh)*V_ + v0 + v];
  }
  __syncthreads();
  int g = tid >> 5, lane = tid & 31;
  for (int t = 0; t < T_; ++t){
    const float* r = rnn + (size_t)t*V_ + v0;
    float s = 0.f;
    for (int v = lane; v < 2000; v += 32) s += r[v]*Wsh[g*2000 + v];
    for (int m = 16; m; m >>= 1) s += __shfl_xor(s, m, 32);
    if (lane == 0) atomicAdd(&ws[WS_X0 + t*EH_ + h0 + g], s);
  }
}

// ---- pre[t,r] = Wih[l] @ x_t + bih + bhh ----
__global__ void __launch_bounds__(832) k_lstm_pre(const float* Wih, const float* bih,
                                                  const float* bhh, const float* emb,
                                                  const float* xin, float* pre, int layer){
  int t = blockIdx.x, tid = threadIdx.x;
  __shared__ __align__(16) float xs[EH_];
  if (tid < EH_) xs[tid] = xin[t*EH_ + tid] + (emb ? emb[tid] : 0.f);
  __syncthreads();
  if (tid < 800){
    const float4* w4 = (const float4*)(Wih + (size_t)layer*160000 + (size_t)tid*200);
    const float4* x4 = (const float4*)xs;
    float a0 = 0.f, a1 = 0.f;
    #pragma unroll 5
    for (int c = 0; c < 50; c += 2){
      float4 w = w4[c],   x = x4[c];
      a0 += w.x*x.x + w.y*x.y + w.z*x.z + w.w*x.w;
      float4 w2 = w4[c+1], x2 = x4[c+1];
      a1 += w2.x*x2.x + w2.y*x2.y + w2.z*x2.z + w2.w*x2.w;
    }
    pre[t*800 + tid] = a0 + a1 + bih[layer*800 + tid] + bhh[layer*800 + tid];
  }
}

// ---- sequential LSTM scan for one layer ----
__global__ void __launch_bounds__(1024) k_lstm_scan(const float* Whh, const float* pre,
                                                    float* xout, int layer){
  int tid = threadIdx.x;
  __shared__ __align__(16) float hs[EH_];
  __shared__ float cs[EH_];
  __shared__ float gs[800];
  if (tid < EH_){ hs[tid] = 0.f; cs[tid] = 0.f; }
  __syncthreads();
  const float4* w4 = (const float4*)(Whh + (size_t)layer*160000 + (size_t)(tid < 800 ? tid : 0)*200);
  for (int t = 0; t < T_; ++t){
    if (tid < 800){
      const float4* h4 = (const float4*)hs;
      float a0 = 0.f, a1 = 0.f;
      #pragma unroll 5
      for (int c = 0; c < 50; c += 2){
        float4 w = w4[c],   h = h4[c];
        a0 += w.x*h.x + w.y*h.y + w.z*h.z + w.w*h.w;
        float4 w2 = w4[c+1], h2 = h4[c+1];
        a1 += w2.x*h2.x + w2.y*h2.y + w2.z*h2.z + w2.w*h2.w;
      }
      gs[tid] = pre[t*800 + tid] + a0 + a1;
    }
    __syncthreads();
    if (tid < EH_){
      float ig = sigf(gs[tid]);
      float fg = sigf(gs[200+tid]);
      float gg = tanhf(gs[400+tid]);
      float og = sigf(gs[600+tid]);
      float cc = fg*cs[tid] + ig*gg;
      cs[tid] = cc;
      float hh = og*tanhf(cc);
      hs[tid] = hh;
      xout[t*EH_ + tid] = hh;
    }
    __syncthreads();
  }
}

// ---- sequential eta chain: etas (T,K) + kl_eta ----
__global__ void __launch_bounds__(256) k_eta_chain(const float* x, const float* Wmu,
                                                   const float* bmu, const float* Wls,
                                                   const float* bls, const float* eps_eta,
                                                   float* ws){
  int tid = threadIdx.x;
  __shared__ float xs[EH_];
  __shared__ float etap[2][K_];
  __shared__ float kls[K_];
  const float log_delta = logf(0.005f);
  const float pvar = expf(log_delta) + 1e-6f;
  int j = tid >> 2, q = tid & 3;
  float klacc = 0.f;
  for (int t = 0; t < T_; ++t){
    if (tid < EH_) xs[tid] = x[t*EH_ + tid];
    __syncthreads();
    int rb = t & 1, wb = rb ^ 1;
    if (j < K_){
      float pm = 0.f, pl = 0.f;
      for (int c = q; c < 250; c += 4){
        float inp = (c < 200) ? xs[c] : ((t == 0) ? 0.f : etap[rb][c-200]);
        pm += Wmu[j*250 + c]*inp;
        pl += Wls[j*250 + c]*inp;
      }
      pm += __shfl_xor(pm, 1, 4); pm += __shfl_xor(pm, 2, 4);
      pl += __shfl_xor(pl, 1, 4); pl += __shfl_xor(pl, 2, 4);
      if (q == 0){
        float mu = pm + bmu[j], lsv = pl + bls[j];
        float klj;
        if (t == 0){
          klj = 0.5f*((expf(lsv) + mu*mu)/(1.f + 1e-6f) - 1.f - lsv);
        } else {
          float d = mu - etap[rb][j];
          klj = 0.5f*((expf(lsv) + d*d)/pvar - 1.f + log_delta - lsv);
        }
        float eta = mu + eps_eta[t*K_ + j]*expf(0.5f*lsv);
        etap[wb][j] = eta;
        kls[j] = klj;
        ws[WS_ETAS + t*K_ + j] = eta;
      }
    }
    __syncthreads();
    if (tid < 64){
      float v = (tid < K_) ? kls[tid] : 0.f;
      for (int m = 32; m; m >>= 1) v += __shfl_xor(v, m, 64);
      if (tid == 0) klacc += v;
    }
    __syncthreads();
  }
  if (tid == 0) ws[WS_SC + 1] = klacc;
}

// ---- h1pre[b,r] partial GEMM over the bow (V) part, atomic accumulate ----
__global__ void __launch_bounds__(256) k_h1_gemm(const float* nb, const float* W1, float* ws){
  // grid (10 vchunks of 2000, 25 rtiles of 32)
  int v0 = blockIdx.x * 2000;
  int r0 = blockIdx.y * 32;
  int tid = threadIdx.x;
  __shared__ __align__(16) float nbs[64*SNB];
  __shared__ __align__(16) float w1s[32*SNB];
  int dg = tid & 15, rg = tid >> 4;
  float acc[2][4] = {};
  for (int vs = 0; vs < 10; ++vs){
    int vbase = v0 + vs*200;
    __syncthreads();
    for (int idx = tid; idx < 64*50; idx += 256){
      int d = idx / 50, qq = idx % 50;
      float4 val = *(const float4*)&nb[(size_t)d*V_ + vbase + 4*qq];
      *(float4*)&nbs[d*SNB + 4*qq] = val;
    }
    for (int idx = tid; idx < 32*100; idx += 256){
      int r = idx / 100, qq = idx % 100;
      float2 val = *(const float2*)&W1[(size_t)(r0+r)*20050 + vbase + 2*qq];
      *(float2*)&w1s[r*SNB + 2*qq] = val;
    }
    __syncthreads();
    for (int v = 0; v < 200; ++v){
      float a0 = w1s[rg*SNB + v];
      float a1 = w1s[(rg+16)*SNB + v];
      #pragma unroll
      for (int jd = 0; jd < 4; ++jd){
        float bb = nbs[(dg + 16*jd)*SNB + v];
        acc[0][jd] += a0*bb;
        acc[1][jd] += a1*bb;
      }
    }
  }
  #pragma unroll
  for (int ir = 0; ir < 2; ++ir)
    #pragma unroll
    for (int jd = 0; jd < 4; ++jd)
      atomicAdd(&ws[WS_H1 + (dg + 16*jd)*TH_ + r0 + rg + 16*ir], acc[ir][jd]);
}

// ---- h1 = relu(h1pre + W1[:,V:] @ eta_td + b1) ----
__global__ void k_h1_final(const float* W1, const float* b1, const int* times, float* ws){
  int idx = blockIdx.x*256 + threadIdx.x;
  if (idx >= B_*TH_) return;
  int b = idx / TH_, r = idx % TH_;
  const float* et = ws + WS_ETAS + times[b]*K_;
  const float* w  = W1 + (size_t)r*20050 + V_;
  float s = ws[WS_H1 + idx] + b1[r];
  for (int k = 0; k < K_; ++k) s += w[k]*et[k];
  ws[WS_H1 + idx] = fmaxf(s, 0.f);
}

// ---- h2 = relu(h1 @ W2^T + b2) ----
__global__ void __launch_bounds__(256) k_h2(const float* W2, const float* b2, float* ws){
  // grid (13 rtiles of 64, 64 docs)
  int r0 = blockIdx.x * 64;
  int b  = blockIdx.y;
  int tid = threadIdx.x;
  __shared__ __align__(16) float h1s[TH_];
  __shared__ float part[4*68];
  for (int i = tid; i < TH_; i += 256) h1s[i] = ws[WS_H1 + b*TH_ + i];
  __syncthreads();
  int rl = tid & 63, p = tid >> 6;
  int r = r0 + rl;
  float acc = 0.f;
  if (r < TH_){
    const float4* w4 = (const float4*)(W2 + (size_t)r*TH_ + p*200);
    const float4* h4 = (const float4*)(h1s + p*200);
    #pragma unroll 5
    for (int c = 0; c < 50; ++c){
      float4 w = w4[c], h = h4[c];
      acc += w.x*h.x + w.y*h.y + w.z*h.z + w.w*h.w;
    }
  }
  part[p*68 + rl] = acc;
  __syncthreads();
  if (tid < 64 && r0 + tid < TH_){
    float s = part[tid] + part[68+tid] + part[136+tid] + part[204+tid] + b2[r0+tid];
    ws[WS_H2 + b*TH_ + r0 + tid] = fmaxf(s, 0.f);
  }
}

// ---- mu_t, ls_t, z, theta(softmax), kl_theta ----
__global__ void __launch_bounds__(128) k_theta(const float* Wmu, const float* bmu,
                                               const float* Wls, const float* bls,
                                               const float* eps_th, const int* times, float* ws){
  int b = blockIdx.x, tid = threadIdx.x;
  __shared__ __align__(16) float h2s[TH_];
  __shared__ float mus[K_], lss[K_];
  for (int i = tid; i < TH_; i += 128) h2s[i] = ws[WS_H2 + b*TH_ + i];
  __syncthreads();
  if (tid < 100){
    int j = (tid < 50) ? tid : tid - 50;
    const float* Wr = (tid < 50) ? (Wmu + j*TH_) : (Wls + j*TH_);
    const float4* w4 = (const float4*)Wr;
    const float4* h4 = (const float4*)h2s;
    float a = 0.f;
    #pragma unroll 5
    for (int c = 0; c < 200; ++c){
      float4 w = w4[c], h = h4[c];
      a += w.x*h.x + w.y*h.y + w.z*h.z + w.w*h.w;
    }
    if (tid < 50) mus[j] = a + bmu[j]; else lss[j] = a + bls[j];
  }
  __syncthreads();
  if (tid < 64){
    int k = tid;
    bool ok = (k < K_);
    float mu  = ok ? mus[k] : 0.f;
    float lsv = ok ? lss[k] : 0.f;
    float etd = ok ? ws[WS_ETAS + times[b]*K_ + k] : 0.f;
    float z   = ok ? (mu + eps_th[b*K_ + k]*expf(0.5f*lsv)) : -1e30f;
    float m = z;
    for (int s = 32; s; s >>= 1) m = fmaxf(m, __shfl_xor(m, s, 64));
    float ez = ok ? expf(z - m) : 0.f;
    float ssum = ez;
    for (int s = 32; s; s >>= 1) ssum += __shfl_xor(ssum, s, 64);
    if (ok) ws[WS_THETA + b*K_ + k] = ez / ssum;
    float d = mu - etd;
    float kl = ok ? 0.5f*((expf(lsv) + d*d)/(1.f + 1e-6f) - 1.f - lsv) : 0.f;
    for (int s = 32; s; s >>= 1) kl += __shfl_xor(kl, s, 64);
    if (tid == 0) atomicAdd(&ws[WS_SC + 2], kl);
  }
}

// ---- pass A: logit tile GEMM + per-(row,vchunk) partial max/sumexp ----
__global__ void __launch_bounds__(256) k_logit_stats(const float* rho, float* ws){
  // grid (157 col-chunks of 128, 40 row-chunks of 64); rows = t*K+k in [0,2500)
  int ct = blockIdx.x, rt = blockIdx.y;
  int row0 = rt*64, col0 = ct*128;
  int tid = threadIdx.x;
  __shared__ __align__(16) float As[64*SA];
  __shared__ __align__(16) float Rs[128*SA];
  int colg = tid & 15, rowg = tid >> 4;
  float acc[4][8] = {};
  const float* alphas = ws + WS_ALPHAS;
  for (int ec = 0; ec < 5; ++ec){
    int e0 = ec*64;
    int esz4 = (ec == 4) ? 11 : 16;
    __syncthreads();
    for (int idx = tid; idx < 64*esz4; idx += 256){
      int r = idx / esz4, qq = idx % esz4;
      int row = row0 + r;
      float4 v = (row < T_*K_) ? *(const float4*)&alphas[(size_t)row*E_ + e0 + 4*qq]
                               : make_float4(0.f,0.f,0.f,0.f);
      *(float4*)&As[r*SA + 4*qq] = v;
    }
    for (int idx = tid; idx < 128*esz4; idx += 256){
      int c = idx / esz4, qq = idx % esz4;
      int col = col0 + c;
      float4 v = (col < V_) ? *(const float4*)&rho[(size_t)col*E_ + e0 + 4*qq]
                            : make_float4(0.f,0.f,0.f,0.f);
      *(float4*)&Rs[c*SA + 4*qq] = v;
    }
    __syncthreads();
    for (int q = 0; q < esz4; ++q){
      float4 av[4], bv[8];
      #pragma unroll
      for (int i = 0; i < 4; ++i) av[i] = *(const float4*)&As[(rowg + 16*i)*SA + 4*q];
      #pragma unroll
      for (int jj = 0; jj < 8; ++jj) bv[jj] = *(const float4*)&Rs[(colg + 16*jj)*SA + 4*q];
      #pragma unroll
      for (int i = 0; i < 4; ++i)
        #pragma unroll
        for (int jj = 0; jj < 8; ++jj)
          acc[i][jj] += av[i].x*bv[jj].x + av[i].y*bv[jj].y + av[i].z*bv[jj].z + av[i].w*bv[jj].w;
    }
  }
  #pragma unroll
  for (int i = 0; i < 4; ++i){
    int row = row0 + rowg + 16*i;
    float rm = -1e30f;
    #pragma unroll
    for (int jj = 0; jj < 8; ++jj){
      int col = col0 + colg + 16*jj;
      if (col < V_) rm = fmaxf(rm, acc[i][jj]);
    }
    for (int m = 1; m < 16; m <<= 1) rm = fmaxf(rm, __shfl_xor(rm, m, 16));
    float sm = 0.f;
    #pragma unroll
    for (int jj = 0; jj < 8; ++jj){
      int col = col0 + colg + 16*jj;
      if (col < V_) sm += expf(acc[i][jj] - rm);
    }
    for (int m = 1; m < 16; m <<= 1) sm += __shfl_xor(sm, m, 16);
    if (colg == 0 && row < T_*K_){
      ws[WS_PM + ct*2500 + row] = rm;
      ws[WS_PS + ct*2500 + row] = sm;
    }
  }
}

// ---- merge partial (m,s) over 157 chunks ----
__global__ void k_stats_merge(float* ws){
  int row = blockIdx.x*8 + (threadIdx.x >> 5);
  int lane = threadIdx.x & 31;
  if (row >= T_*K_) return;
  float m = -1e30f;
  for (int i = lane; i < 157; i += 32) m = fmaxf(m, ws[WS_PM + i*2500 + row]);
  for (int s = 16; s; s >>= 1) m = fmaxf(m, __shfl_xor(m, s, 32));
  float ssum = 0.f;
  for (int i = lane; i < 157; i += 32)
    ssum += ws[WS_PS + i*2500 + row]*expf(ws[WS_PM + i*2500 + row] - m);
  for (int s = 16; s; s >>= 1) ssum += __shfl_xor(ssum, s, 32);
  if (lane == 0){ ws[WS_M + row] = m; ws[WS_S + row] = ssum; }
}

// ---- pass B: recompute logit for needed t, form beta, accumulate NLL ----
__global__ void __launch_bounds__(256) k_lik(const float* rho, const float* nb,
                                             const int* times, float* ws){
  // grid (313 col-chunks of 64, 50 t)
  int ct = blockIdx.x, t = blockIdx.y;
  int col0 = ct*64;
  int tid = threadIdx.x;
  __shared__ unsigned long long dmask;
  bool pred = (tid < B_) && (times[tid < B_ ? tid : 0] == t);
  unsigned long long mk = __ballot(pred);
  if (tid == 0) dmask = mk;
  __syncthreads();
  unsigned long long mask = dmask;
  if (mask == 0ull) return;

  __shared__ __align__(16) float As[64*SA];
  __shared__ __align__(16) float Rs[64*SA];
  __shared__ float P[50*SA];
  __shared__ float Qs[4*68];
  int colg = tid & 15, rowg = tid >> 4;
  float acc[4][4] = {};
  for (int ec = 0; ec < 5; ++ec){
    int e0 = ec*64;
    int esz4 = (ec == 4) ? 11 : 16;
    __syncthreads();
    for (int idx = tid; idx < 64*esz4; idx += 256){
      int r = idx / esz4, qq = idx % esz4;
      float4 v = (r < K_) ? *(const float4*)&ws[WS_ALPHAS + (size_t)(t*K_ + r)*E_ + e0 + 4*qq]
                          : make_float4(0.f,0.f,0.f,0.f);
      *(float4*)&As[r*SA + 4*qq] = v;
    }
    for (int idx = tid; idx < 64*esz4; idx += 256){
      int c = idx / esz4, qq = idx % esz4;
      int col = col0 + c;
      float4 v = (col < V_) ? *(const float4*)&rho[(size_t)col*E_ + e0 + 4*qq]
                            : make_float4(0.f,0.f,0.f,0.f);
      *(float4*)&Rs[c*SA + 4*qq] = v;
    }
    __syncthreads();
    for (int q = 0; q < esz4; ++q){
      float4 av[4], bv[4];
      #pragma unroll
      for (int i = 0; i < 4; ++i) av[i] = *(const float4*)&As[(rowg + 16*i)*SA + 4*q];
      #pragma unroll
      for (int jj = 0; jj < 4; ++jj) bv[jj] = *(const float4*)&Rs[(colg + 16*jj)*SA + 4*q];
      #pragma unroll
      for (int i = 0; i < 4; ++i)
        #pragma unroll
        for (int jj = 0; jj < 4; ++jj)
          acc[i][jj] += av[i].x*bv[jj].x + av[i].y*bv[jj].y + av[i].z*bv[jj].z + av[i].w*bv[jj].w;
    }
  }
  // beta values for this tile
  #pragma unroll
  for (int i = 0; i < 4; ++i){
    int r = rowg + 16*i;
    if (r < K_){
      float mm = ws[WS_M + t*K_ + r];
      float si = 1.f / ws[WS_S + t*K_ + r];
      #pragma unroll
      for (int jj = 0; jj < 4; ++jj){
        int col = col0 + colg + 16*jj;
        if (col < V_) P[r*SA + colg + 16*jj] = expf(acc[i][jj] - mm)*si;
      }
    }
  }
  __syncthreads();
  float nllloc = 0.f;
  int cl = tid & 63, kk = tid >> 6;
  for (unsigned long long m2 = mask; m2; m2 &= (m2-1)){
    int b = __ffsll((long long)m2) - 1;
    float partial = 0.f;
    for (int k = kk; k < K_; k += 4)
      partial += ws[WS_THETA + b*K_ + k]*P[k*SA + cl];
    Qs[kk*68 + cl] = partial;
    __syncthreads();
    if (tid < 64){
      float qv = Qs[cl] + Qs[68+cl] + Qs[136+cl] + Qs[204+cl];
      int col = col0 + cl;
      float term = (col < V_) ? (-logf(qv + 1e-6f)*nb[(size_t)b*V_ + col]) : 0.f;
      for (int s2 = 32; s2; s2 >>= 1) term += __shfl_xor(term, s2, 64);
      if (tid == 0) nllloc += term;
    }
    __syncthreads();
  }
  if (tid == 0) atomicAdd(&ws[WS_SC + 3], nllloc);
}

// ---- assemble outputs ----
__global__ void k_final(const float* ws, float* out){
  if (threadIdx.x == 0 && blockIdx.x == 0){
    float nll = ws[WS_SC+3] / (float)B_;
    float kla = ws[WS_SC+0];
    float kle = ws[WS_SC+1];
    float klt = ws[WS_SC+2] / (float)B_;
    out[0] = nll + kla + kle + klt;
    out[1] = nll;
    out[2] = kla;
    out[3] = kle;
    out[4] = klt;
  }
}

// ------------------------------------------------------------------
extern "C" void kernel_launch(void* const* d_in, const int* in_sizes, int n_in,
                              void* d_out, int out_size, void* d_ws, size_t ws_size,
                              hipStream_t stream){
  const float* nb    = (const float*)d_in[1];
  const int*   times = (const int*)d_in[2];
  const float* rnn   = (const float*)d_in[3];
  const float* eps_a = (const float*)d_in[5];
  const float* eps_e = (const float*)d_in[6];
  const float* eps_t = (const float*)d_in[7];
  const float* rho   = (const float*)d_in[8];
  const float* mqa   = (const float*)d_in[9];
  const float* lqa   = (const float*)d_in[10];
  const float* W1    = (const float*)d_in[11];
  const float* b1    = (const float*)d_in[12];
  const float* W2    = (const float*)d_in[13];
  const float* b2    = (const float*)d_in[14];
  const float* Wmt   = (const float*)d_in[15];
  const float* bmt   = (const float*)d_in[16];
  const float* Wlt   = (const float*)d_in[17];
  const float* blt   = (const float*)d_in[18];
  const float* Wem   = (const float*)d_in[19];
  const float* bem   = (const float*)d_in[20];
  const float* Wih   = (const float*)d_in[21];
  const float* Whh   = (const float*)d_in[22];
  const float* bih   = (const float*)d_in[23];
  const float* bhh   = (const float*)d_in[24];
  const float* Wme   = (const float*)d_in[25];
  const float* bme   = (const float*)d_in[26];
  const float* Wle   = (const float*)d_in[27];
  const float* ble   = (const float*)d_in[28];
  float* ws  = (float*)d_ws;
  float* out = (float*)d_out;

  k_zero<<<dim3(240), dim3(256), 0, stream>>>(ws);
  k_alpha<<<dim3(2500), dim3(256), 0, stream>>>(mqa, lqa, eps_a, ws);
  k_eta_map<<<dim3(10,25), dim3(256), 0, stream>>>(rnn, Wem, ws);

  float* x0  = ws + WS_X0;
  float* x1  = ws + WS_X1;
  float* pre = ws + WS_PRE;
  k_lstm_pre<<<dim3(50), dim3(832), 0, stream>>>(Wih, bih, bhh, bem, x0, pre, 0);
  k_lstm_scan<<<dim3(1), dim3(1024), 0, stream>>>(Whh, pre, x1, 0);
  k_lstm_pre<<<dim3(50), dim3(832), 0, stream>>>(Wih, bih, bhh, (const float*)nullptr, x1, pre, 1);
  k_lstm_scan<<<dim3(1), dim3(1024), 0, stream>>>(Whh, pre, x0, 1);
  k_lstm_pre<<<dim3(50), dim3(832), 0, stream>>>(Wih, bih, bhh, (const float*)nullptr, x0, pre, 2);
  k_lstm_scan<<<dim3(1), dim3(1024), 0, stream>>>(Whh, pre, x1, 2);

  k_eta_chain<<<dim3(1), dim3(256), 0, stream>>>(x1, Wme, bme, Wle, ble, eps_e, ws);

  k_h1_gemm<<<dim3(10,25), dim3(256), 0, stream>>>(nb, W1, ws);
  k_h1_final<<<dim3(200), dim3(256), 0, stream>>>(W1, b1, times, ws);
  k_h2<<<dim3(13,64), dim3(256), 0, stream>>>(W2, b2, ws);
  k_theta<<<dim3(64), dim3(128), 0, stream>>>(Wmt, bmt, Wlt, blt, eps_t, times, ws);

  k_logit_stats<<<dim3(157,40), dim3(256), 0, stream>>>(rho, ws);
  k_stats_merge<<<dim3(313), dim3(256), 0, stream>>>(ws);
  k_lik<<<dim3(313,50), dim3(256), 0, stream>>>(rho, nb, times, ws);

  k_final<<<dim3(1), dim3(64), 0, stream>>>(ws, out);
}

// Round 4
// 4063.581 us; speedup vs baseline: 1.2305x; 1.2305x over previous
//
#include <hip/hip_runtime.h>
#include <math.h>

#define V_ 20000
#define K_ 50
#define T_ 50
#define E_ 300
#define TH_ 800
#define EH_ 200
#define B_ 64

// ---- workspace layout (float offsets) ----
#define WS_SC      0        // [0]=kl_alpha [1]=kl_eta [2]=kl_theta_sum [3]=nll_sum
#define WS_ALPHAS  8        // 750000
#define WS_X0      750008   // 10000
#define WS_X1      760008   // 10000
#define WS_PRE     770008   // 40000
#define WS_ETAS    810008   // 2500
#define WS_H1      812508   // 51200
#define WS_H2      863708   // 51200
#define WS_THETA   914908   // 3200
#define WS_M       918108   // 2500
#define WS_S       920608   // 2500
#define WS_PM      923108   // 157*2500 = 392500
#define WS_PS      1315608  // 392500   -> total 1708108 floats (~6.8 MB)
// eta-map partials alias the PM/PS region (dead until k_logit_stats runs)
#define WS_EPART   WS_PM    // 40*10000 = 400000 floats
// present-t bitmap (ints) aliases WS_PRE (dead after LSTM phase)
#define WS_TPRES   WS_PRE

#define SA 68     // LDS row stride (floats) for GEMM tiles: 16B-aligned, <=2-way bank conflicts
#define SNB 204   // LDS row stride for h1 gemm tiles
#define VC 512    // eta-map v-chunk

__device__ __forceinline__ float sigf(float x){ return 1.0f/(1.0f+expf(-x)); }

// ------------------------------------------------------------------
__global__ void k_zero(float* ws){
  int i = blockIdx.x*256 + threadIdx.x;
  if (i < 8) ws[WS_SC + i] = 0.f;
  else if (i < 8 + 51200) ws[WS_H1 + (i-8)] = 0.f;
}

// ---- alphas = mu + eps*exp(0.5 ls); kl_alpha ----
__global__ void __launch_bounds__(256) k_alpha(const float* mu_q, const float* ls_q,
                                               const float* eps, float* ws){
  int bid = blockIdx.x; int t = bid / K_, k = bid % K_;
  int tid = threadIdx.x;
  const float log_delta = logf(0.005f);
  const float pvar = expf(log_delta) + 1e-6f;
  float kl = 0.f;
  for (int e = tid; e < E_; e += 256){
    float mu = mu_q[(k*T_ + t)*E_ + e];
    float ls = ls_q[(k*T_ + t)*E_ + e];
    float ep = eps[(t*K_ + k)*E_ + e];
    float al = mu + ep*expf(0.5f*ls);
    ws[WS_ALPHAS + (t*K_ + k)*E_ + e] = al;
    if (t == 0){
      kl += 0.5f*((expf(ls) + mu*mu)/(1.f + 1e-6f) - 1.f - ls);
    } else {
      float mup = mu_q[(k*T_ + (t-1))*E_ + e];
      float lsp = ls_q[(k*T_ + (t-1))*E_ + e];
      float epp = eps[((t-1)*K_ + k)*E_ + e];
      float ap  = mup + epp*expf(0.5f*lsp);
      float d = mu - ap;
      kl += 0.5f*((expf(ls) + d*d)/pvar - 1.f + log_delta - ls);
    }
  }
  __shared__ float red[256];
  red[tid] = kl; __syncthreads();
  for (int s = 128; s; s >>= 1){ if (tid < s) red[tid] += red[tid+s]; __syncthreads(); }
  if (tid == 0) atomicAdd(&ws[WS_SC + 0], red[0]);
}

// ---- eta_map GEMM: partial[vc][t][h] = rnn[t, v-chunk] . W[h, v-chunk] ----
__global__ void __launch_bounds__(256) k_eta_gemm(const float* rnn, const float* W, float* ws){
  // grid (40 vchunks of 512, 25 htiles of 8, 2 tslabs of 25)
  int vc = blockIdx.x;
  int h0 = blockIdx.y * 8;
  int t0 = blockIdx.z * 25;
  int v0 = vc * VC;
  int valid4 = (V_ - v0 >= VC) ? (VC >> 2) : ((V_ - v0) >> 2);  // 128 or 8
  int tid = threadIdx.x;
  __shared__ __align__(16) float rs[25*VC];   // 51.2 KB
  for (int idx = tid; idx < 25*128; idx += 256){
    int r = idx >> 7, c = idx & 127;
    float4 v = (c < valid4) ? *(const float4*)&rnn[(size_t)(t0 + r)*V_ + v0 + 4*c]
                            : make_float4(0.f,0.f,0.f,0.f);
    *(float4*)&rs[r*VC + 4*c] = v;
  }
  int g = tid >> 5, lane = tid & 31;   // group g owns h = h0+g
  float4 wreg[4];
  #pragma unroll
  for (int i = 0; i < 4; ++i){
    int c4 = lane + 32*i;
    wreg[i] = (c4 < valid4) ? *(const float4*)&W[(size_t)(h0+g)*V_ + v0 + 4*c4]
                            : make_float4(0.f,0.f,0.f,0.f);
  }
  __syncthreads();
  for (int tl = 0; tl < 25; ++tl){
    const float* rrow = rs + tl*VC;
    float s = 0.f;
    #pragma unroll
    for (int i = 0; i < 4; ++i){
      float4 a = *(const float4*)&rrow[4*(lane + 32*i)];
      s += a.x*wreg[i].x + a.y*wreg[i].y + a.z*wreg[i].z + a.w*wreg[i].w;
    }
    #pragma unroll
    for (int m = 16; m; m >>= 1) s += __shfl_xor(s, m, 32);
    if (lane == 0) ws[WS_EPART + vc*(T_*EH_) + (t0 + tl)*EH_ + h0 + g] = s;
  }
}

// ---- merge eta partials -> x0 ----
__global__ void k_eta_merge(float* ws){
  int idx = blockIdx.x*256 + threadIdx.x;
  if (idx >= T_*EH_) return;
  float s = 0.f;
  for (int vc = 0; vc < 40; ++vc) s += ws[WS_EPART + vc*(T_*EH_) + idx];
  ws[WS_X0 + idx] = s;
}

// ---- pre[t,r] = Wih[l] @ x_t + bih + bhh ----
__global__ void __launch_bounds__(832) k_lstm_pre(const float* Wih, const float* bih,
                                                  const float* bhh, const float* emb,
                                                  const float* xin, float* pre, int layer){
  int t = blockIdx.x, tid = threadIdx.x;
  __shared__ __align__(16) float xs[EH_];
  if (tid < EH_) xs[tid] = xin[t*EH_ + tid] + (emb ? emb[tid] : 0.f);
  __syncthreads();
  if (tid < 800){
    const float4* w4 = (const float4*)(Wih + (size_t)layer*160000 + (size_t)tid*200);
    const float4* x4 = (const float4*)xs;
    float a0 = 0.f, a1 = 0.f;
    #pragma unroll 5
    for (int c = 0; c < 50; c += 2){
      float4 w = w4[c],   x = x4[c];
      a0 += w.x*x.x + w.y*x.y + w.z*x.z + w.w*x.w;
      float4 w2 = w4[c+1], x2 = x4[c+1];
      a1 += w2.x*x2.x + w2.y*x2.y + w2.z*x2.z + w2.w*x2.w;
    }
    pre[t*800 + tid] = a0 + a1 + bih[layer*800 + tid] + bhh[layer*800 + tid];
  }
}

// ---- sequential LSTM scan for one layer (validated round-1 version) ----
__global__ void __launch_bounds__(1024) k_lstm_scan(const float* Whh, const float* pre,
                                                    float* xout, int layer){
  int tid = threadIdx.x;
  __shared__ __align__(16) float hs[EH_];
  __shared__ float cs[EH_];
  __shared__ float gs[800];
  if (tid < EH_){ hs[tid] = 0.f; cs[tid] = 0.f; }
  __syncthreads();
  const float4* w4 = (const float4*)(Whh + (size_t)layer*160000 + (size_t)(tid < 800 ? tid : 0)*200);
  for (int t = 0; t < T_; ++t){
    if (tid < 800){
      const float4* h4 = (const float4*)hs;
      float a0 = 0.f, a1 = 0.f;
      #pragma unroll 5
      for (int c = 0; c < 50; c += 2){
        float4 w = w4[c],   h = h4[c];
        a0 += w.x*h.x + w.y*h.y + w.z*h.z + w.w*h.w;
        float4 w2 = w4[c+1], h2 = h4[c+1];
        a1 += w2.x*h2.x + w2.y*h2.y + w2.z*h2.z + w2.w*h2.w;
      }
      gs[tid] = pre[t*800 + tid] + a0 + a1;
    }
    __syncthreads();
    if (tid < EH_){
      float ig = sigf(gs[tid]);
      float fg = sigf(gs[200+tid]);
      float gg = tanhf(gs[400+tid]);
      float og = sigf(gs[600+tid]);
      float cc = fg*cs[tid] + ig*gg;
      cs[tid] = cc;
      float hh = og*tanhf(cc);
      hs[tid] = hh;
      xout[t*EH_ + tid] = hh;
    }
    __syncthreads();
  }
}

// ---- sequential eta chain: etas (T,K) + kl_eta ----
__global__ void __launch_bounds__(256) k_eta_chain(const float* x, const float* Wmu,
                                                   const float* bmu, const float* Wls,
                                                   const float* bls, const float* eps_eta,
                                                   float* ws){
  int tid = threadIdx.x;
  __shared__ float xs[EH_];
  __shared__ float etap[2][K_];
  __shared__ float kls[K_];
  const float log_delta = logf(0.005f);
  const float pvar = expf(log_delta) + 1e-6f;
  int j = tid >> 2, q = tid & 3;
  float klacc = 0.f;
  for (int t = 0; t < T_; ++t){
    if (tid < EH_) xs[tid] = x[t*EH_ + tid];
    __syncthreads();
    int rb = t & 1, wb = rb ^ 1;
    if (j < K_){
      float pm = 0.f, pl = 0.f;
      for (int c = q; c < 250; c += 4){
        float inp = (c < 200) ? xs[c] : ((t == 0) ? 0.f : etap[rb][c-200]);
        pm += Wmu[j*250 + c]*inp;
        pl += Wls[j*250 + c]*inp;
      }
      pm += __shfl_xor(pm, 1, 4); pm += __shfl_xor(pm, 2, 4);
      pl += __shfl_xor(pl, 1, 4); pl += __shfl_xor(pl, 2, 4);
      if (q == 0){
        float mu = pm + bmu[j], lsv = pl + bls[j];
        float klj;
        if (t == 0){
          klj = 0.5f*((expf(lsv) + mu*mu)/(1.f + 1e-6f) - 1.f - lsv);
        } else {
          float d = mu - etap[rb][j];
          klj = 0.5f*((expf(lsv) + d*d)/pvar - 1.f + log_delta - lsv);
        }
        float eta = mu + eps_eta[t*K_ + j]*expf(0.5f*lsv);
        etap[wb][j] = eta;
        kls[j] = klj;
        ws[WS_ETAS + t*K_ + j] = eta;
      }
    }
    __syncthreads();
    if (tid < 64){
      float v = (tid < K_) ? kls[tid] : 0.f;
      for (int m = 32; m; m >>= 1) v += __shfl_xor(v, m, 64);
      if (tid == 0) klacc += v;
    }
    __syncthreads();
  }
  if (tid == 0) ws[WS_SC + 1] = klacc;
}

// ---- present-t bitmap (into WS_TPRES, dead PRE region) ----
__global__ void k_tmask(const int* times, float* ws){
  int t = threadIdx.x;
  if (t < T_){
    int p = 0;
    for (int b = 0; b < B_; ++b) p |= (times[b] == t) ? 1 : 0;
    ((int*)ws)[WS_TPRES + t] = p;
  }
}

// ---- h1pre[b,r] partial GEMM over the bow (V) part, atomic accumulate ----
__global__ void __launch_bounds__(256) k_h1_gemm(const float* nb, const float* W1, float* ws){
  // grid (10 vchunks of 2000, 25 rtiles of 32)
  int v0 = blockIdx.x * 2000;
  int r0 = blockIdx.y * 32;
  int tid = threadIdx.x;
  __shared__ __align__(16) float nbs[64*SNB];
  __shared__ __align__(16) float w1s[32*SNB];
  int dg = tid & 15, rg = tid >> 4;
  float acc[2][4] = {};
  for (int vs = 0; vs < 10; ++vs){
    int vbase = v0 + vs*200;
    __syncthreads();
    for (int idx = tid; idx < 64*50; idx += 256){
      int d = idx / 50, qq = idx % 50;
      float4 val = *(const float4*)&nb[(size_t)d*V_ + vbase + 4*qq];
      *(float4*)&nbs[d*SNB + 4*qq] = val;
    }
    for (int idx = tid; idx < 32*100; idx += 256){
      int r = idx / 100, qq = idx % 100;
      float2 val = *(const float2*)&W1[(size_t)(r0+r)*20050 + vbase + 2*qq];
      *(float2*)&w1s[r*SNB + 2*qq] = val;
    }
    __syncthreads();
    for (int v = 0; v < 200; ++v){
      float a0 = w1s[rg*SNB + v];
      float a1 = w1s[(rg+16)*SNB + v];
      #pragma unroll
      for (int jd = 0; jd < 4; ++jd){
        float bb = nbs[(dg + 16*jd)*SNB + v];
        acc[0][jd] += a0*bb;
        acc[1][jd] += a1*bb;
      }
    }
  }
  #pragma unroll
  for (int ir = 0; ir < 2; ++ir)
    #pragma unroll
    for (int jd = 0; jd < 4; ++jd)
      atomicAdd(&ws[WS_H1 + (dg + 16*jd)*TH_ + r0 + rg + 16*ir], acc[ir][jd]);
}

// ---- h1 = relu(h1pre + W1[:,V:] @ eta_td + b1) ----
__global__ void k_h1_final(const float* W1, const float* b1, const int* times, float* ws){
  int idx = blockIdx.x*256 + threadIdx.x;
  if (idx >= B_*TH_) return;
  int b = idx / TH_, r = idx % TH_;
  const float* et = ws + WS_ETAS + times[b]*K_;
  const float* w  = W1 + (size_t)r*20050 + V_;
  float s = ws[WS_H1 + idx] + b1[r];
  for (int k = 0; k < K_; ++k) s += w[k]*et[k];
  ws[WS_H1 + idx] = fmaxf(s, 0.f);
}

// ---- h2 = relu(h1 @ W2^T + b2) ----
__global__ void __launch_bounds__(256) k_h2(const float* W2, const float* b2, float* ws){
  // grid (13 rtiles of 64, 64 docs)
  int r0 = blockIdx.x * 64;
  int b  = blockIdx.y;
  int tid = threadIdx.x;
  __shared__ __align__(16) float h1s[TH_];
  __shared__ float part[4*68];
  for (int i = tid; i < TH_; i += 256) h1s[i] = ws[WS_H1 + b*TH_ + i];
  __syncthreads();
  int rl = tid & 63, p = tid >> 6;
  int r = r0 + rl;
  float acc = 0.f;
  if (r < TH_){
    const float4* w4 = (const float4*)(W2 + (size_t)r*TH_ + p*200);
    const float4* h4 = (const float4*)(h1s + p*200);
    #pragma unroll 5
    for (int c = 0; c < 50; ++c){
      float4 w = w4[c], h = h4[c];
      acc += w.x*h.x + w.y*h.y + w.z*h.z + w.w*h.w;
    }
  }
  part[p*68 + rl] = acc;
  __syncthreads();
  if (tid < 64 && r0 + tid < TH_){
    float s = part[tid] + part[68+tid] + part[136+tid] + part[204+tid] + b2[r0+tid];
    ws[WS_H2 + b*TH_ + r0 + tid] = fmaxf(s, 0.f);
  }
}

// ---- mu_t, ls_t, z, theta(softmax), kl_theta ----
__global__ void __launch_bounds__(128) k_theta(const float* Wmu, const float* bmu,
                                               const float* Wls, const float* bls,
                                               const float* eps_th, const int* times, float* ws){
  int b = blockIdx.x, tid = threadIdx.x;
  __shared__ __align__(16) float h2s[TH_];
  __shared__ float mus[K_], lss[K_];
  for (int i = tid; i < TH_; i += 128) h2s[i] = ws[WS_H2 + b*TH_ + i];
  __syncthreads();
  if (tid < 100){
    int j = (tid < 50) ? tid : tid - 50;
    const float* Wr = (tid < 50) ? (Wmu + j*TH_) : (Wls + j*TH_);
    const float4* w4 = (const float4*)Wr;
    const float4* h4 = (const float4*)h2s;
    float a = 0.f;
    #pragma unroll 5
    for (int c = 0; c < 200; ++c){
      float4 w = w4[c], h = h4[c];
      a += w.x*h.x + w.y*h.y + w.z*h.z + w.w*h.w;
    }
    if (tid < 50) mus[j] = a + bmu[j]; else lss[j] = a + bls[j];
  }
  __syncthreads();
  if (tid < 64){
    int k = tid;
    bool ok = (k < K_);
    float mu  = ok ? mus[k] : 0.f;
    float lsv = ok ? lss[k] : 0.f;
    float etd = ok ? ws[WS_ETAS + times[b]*K_ + k] : 0.f;
    float z   = ok ? (mu + eps_th[b*K_ + k]*expf(0.5f*lsv)) : -1e30f;
    float m = z;
    for (int s = 32; s; s >>= 1) m = fmaxf(m, __shfl_xor(m, s, 64));
    float ez = ok ? expf(z - m) : 0.f;
    float ssum = ez;
    for (int s = 32; s; s >>= 1) ssum += __shfl_xor(ssum, s, 64);
    if (ok) ws[WS_THETA + b*K_ + k] = ez / ssum;
    float d = mu - etd;
    float kl = ok ? 0.5f*((expf(lsv) + d*d)/(1.f + 1e-6f) - 1.f - lsv) : 0.f;
    for (int s = 32; s; s >>= 1) kl += __shfl_xor(kl, s, 64);
    if (tid == 0) atomicAdd(&ws[WS_SC + 2], kl);
  }
}

// ---- pass A: logit tile GEMM + per-(row,vchunk) partial max/sumexp ----
__global__ void __launch_bounds__(256) k_logit_stats(const float* rho, float* ws){
  // grid (157 col-chunks of 128, 40 row-chunks of 64); rows = t*K+k in [0,2500)
  int ct = blockIdx.x, rt = blockIdx.y;
  int row0 = rt*64, col0 = ct*128;
  // skip chunks whose t-range is entirely absent from `times`
  {
    const int* pres = (const int*)ws + WS_TPRES;
    int tA = row0 / K_;
    int tB = (row0 + 63) / K_; if (tB > T_-1) tB = T_-1;
    bool need = false;
    for (int tt = tA; tt <= tB; ++tt) need = need || (pres[tt] != 0);
    if (!need) return;
  }
  int tid = threadIdx.x;
  __shared__ __align__(16) float As[64*SA];
  __shared__ __align__(16) float Rs[128*SA];
  int colg = tid & 15, rowg = tid >> 4;
  float acc[4][8] = {};
  const float* alphas = ws + WS_ALPHAS;
  for (int ec = 0; ec < 5; ++ec){
    int e0 = ec*64;
    int esz4 = (ec == 4) ? 11 : 16;
    __syncthreads();
    for (int idx = tid; idx < 64*esz4; idx += 256){
      int r = idx / esz4, qq = idx % esz4;
      int row = row0 + r;
      float4 v = (row < T_*K_) ? *(const float4*)&alphas[(size_t)row*E_ + e0 + 4*qq]
                               : make_float4(0.f,0.f,0.f,0.f);
      *(float4*)&As[r*SA + 4*qq] = v;
    }
    for (int idx = tid; idx < 128*esz4; idx += 256){
      int c = idx / esz4, qq = idx % esz4;
      int col = col0 + c;
      float4 v = (col < V_) ? *(const float4*)&rho[(size_t)col*E_ + e0 + 4*qq]
                            : make_float4(0.f,0.f,0.f,0.f);
      *(float4*)&Rs[c*SA + 4*qq] = v;
    }
    __syncthreads();
    for (int q = 0; q < esz4; ++q){
      float4 av[4], bv[8];
      #pragma unroll
      for (int i = 0; i < 4; ++i) av[i] = *(const float4*)&As[(rowg + 16*i)*SA + 4*q];
      #pragma unroll
      for (int jj = 0; jj < 8; ++jj) bv[jj] = *(const float4*)&Rs[(colg + 16*jj)*SA + 4*q];
      #pragma unroll
      for (int i = 0; i < 4; ++i)
        #pragma unroll
        for (int jj = 0; jj < 8; ++jj)
          acc[i][jj] += av[i].x*bv[jj].x + av[i].y*bv[jj].y + av[i].z*bv[jj].z + av[i].w*bv[jj].w;
    }
  }
  #pragma unroll
  for (int i = 0; i < 4; ++i){
    int row = row0 + rowg + 16*i;
    float rm = -1e30f;
    #pragma unroll
    for (int jj = 0; jj < 8; ++jj){
      int col = col0 + colg + 16*jj;
      if (col < V_) rm = fmaxf(rm, acc[i][jj]);
    }
    for (int m = 1; m < 16; m <<= 1) rm = fmaxf(rm, __shfl_xor(rm, m, 16));
    float sm = 0.f;
    #pragma unroll
    for (int jj = 0; jj < 8; ++jj){
      int col = col0 + colg + 16*jj;
      if (col < V_) sm += expf(acc[i][jj] - rm);
    }
    for (int m = 1; m < 16; m <<= 1) sm += __shfl_xor(sm, m, 16);
    if (colg == 0 && row < T_*K_){
      ws[WS_PM + ct*2500 + row] = rm;
      ws[WS_PS + ct*2500 + row] = sm;
    }
  }
}

// ---- merge partial (m,s) over 157 chunks ----
__global__ void k_stats_merge(float* ws){
  int row = blockIdx.x*8 + (threadIdx.x >> 5);
  int lane = threadIdx.x & 31;
  if (row >= T_*K_) return;
  float m = -1e30f;
  for (int i = lane; i < 157; i += 32) m = fmaxf(m, ws[WS_PM + i*2500 + row]);
  for (int s = 16; s; s >>= 1) m = fmaxf(m, __shfl_xor(m, s, 32));
  float ssum = 0.f;
  for (int i = lane; i < 157; i += 32)
    ssum += ws[WS_PS + i*2500 + row]*expf(ws[WS_PM + i*2500 + row] - m);
  for (int s = 16; s; s >>= 1) ssum += __shfl_xor(ssum, s, 32);
  if (lane == 0){ ws[WS_M + row] = m; ws[WS_S + row] = ssum; }
}

// ---- pass B: recompute logit for needed t, form beta, accumulate NLL ----
__global__ void __launch_bounds__(256) k_lik(const float* rho, const float* nb,
                                             const int* times, float* ws){
  // grid (313 col-chunks of 64, 50 t)
  int ct = blockIdx.x, t = blockIdx.y;
  int col0 = ct*64;
  int tid = threadIdx.x;
  __shared__ unsigned long long dmask;
  bool pred = (tid < B_) && (times[tid < B_ ? tid : 0] == t);
  unsigned long long mk = __ballot(pred);
  if (tid == 0) dmask = mk;
  __syncthreads();
  unsigned long long mask = dmask;
  if (mask == 0ull) return;

  __shared__ __align__(16) float As[64*SA];
  __shared__ __align__(16) float Rs[64*SA];
  __shared__ float P[50*SA];
  __shared__ float Qs[4*68];
  int colg = tid & 15, rowg = tid >> 4;
  float acc[4][4] = {};
  for (int ec = 0; ec < 5; ++ec){
    int e0 = ec*64;
    int esz4 = (ec == 4) ? 11 : 16;
    __syncthreads();
    for (int idx = tid; idx < 64*esz4; idx += 256){
      int r = idx / esz4, qq = idx % esz4;
      float4 v = (r < K_) ? *(const float4*)&ws[WS_ALPHAS + (size_t)(t*K_ + r)*E_ + e0 + 4*qq]
                          : make_float4(0.f,0.f,0.f,0.f);
      *(float4*)&As[r*SA + 4*qq] = v;
    }
    for (int idx = tid; idx < 64*esz4; idx += 256){
      int c = idx / esz4, qq = idx % esz4;
      int col = col0 + c;
      float4 v = (col < V_) ? *(const float4*)&rho[(size_t)col*E_ + e0 + 4*qq]
                            : make_float4(0.f,0.f,0.f,0.f);
      *(float4*)&Rs[c*SA + 4*qq] = v;
    }
    __syncthreads();
    for (int q = 0; q < esz4; ++q){
      float4 av[4], bv[4];
      #pragma unroll
      for (int i = 0; i < 4; ++i) av[i] = *(const float4*)&As[(rowg + 16*i)*SA + 4*q];
      #pragma unroll
      for (int jj = 0; jj < 4; ++jj) bv[jj] = *(const float4*)&Rs[(colg + 16*jj)*SA + 4*q];
      #pragma unroll
      for (int i = 0; i < 4; ++i)
        #pragma unroll
        for (int jj = 0; jj < 4; ++jj)
          acc[i][jj] += av[i].x*bv[jj].x + av[i].y*bv[jj].y + av[i].z*bv[jj].z + av[i].w*bv[jj].w;
    }
  }
  #pragma unroll
  for (int i = 0; i < 4; ++i){
    int r = rowg + 16*i;
    if (r < K_){
      float mm = ws[WS_M + t*K_ + r];
      float si = 1.f / ws[WS_S + t*K_ + r];
      #pragma unroll
      for (int jj = 0; jj < 4; ++jj){
        int col = col0 + colg + 16*jj;
        if (col < V_) P[r*SA + colg + 16*jj] = expf(acc[i][jj] - mm)*si;
      }
    }
  }
  __syncthreads();
  float nllloc = 0.f;
  int cl = tid & 63, kk = tid >> 6;
  for (unsigned long long m2 = mask; m2; m2 &= (m2-1)){
    int b = __ffsll((long long)m2) - 1;
    float partial = 0.f;
    for (int k = kk; k < K_; k += 4)
      partial += ws[WS_THETA + b*K_ + k]*P[k*SA + cl];
    Qs[kk*68 + cl] = partial;
    __syncthreads();
    if (tid < 64){
      float qv = Qs[cl] + Qs[68+cl] + Qs[136+cl] + Qs[204+cl];
      int col = col0 + cl;
      float term = (col < V_) ? (-logf(qv + 1e-6f)*nb[(size_t)b*V_ + col]) : 0.f;
      for (int s2 = 32; s2; s2 >>= 1) term += __shfl_xor(term, s2, 64);
      if (tid == 0) nllloc += term;
    }
    __syncthreads();
  }
  if (tid == 0) atomicAdd(&ws[WS_SC + 3], nllloc);
}

// ---- assemble outputs ----
__global__ void k_final(const float* ws, float* out){
  if (threadIdx.x == 0 && blockIdx.x == 0){
    float nll = ws[WS_SC+3] / (float)B_;
    float kla = ws[WS_SC+0];
    float kle = ws[WS_SC+1];
    float klt = ws[WS_SC+2] / (float)B_;
    out[0] = nll + kla + kle + klt;
    out[1] = nll;
    out[2] = kla;
    out[3] = kle;
    out[4] = klt;
  }
}

// ------------------------------------------------------------------
extern "C" void kernel_launch(void* const* d_in, const int* in_sizes, int n_in,
                              void* d_out, int out_size, void* d_ws, size_t ws_size,
                              hipStream_t stream){
  const float* nb    = (const float*)d_in[1];
  const int*   times = (const int*)d_in[2];
  const float* rnn   = (const float*)d_in[3];
  const float* eps_a = (const float*)d_in[5];
  const float* eps_e = (const float*)d_in[6];
  const float* eps_t = (const float*)d_in[7];
  const float* rho   = (const float*)d_in[8];
  const float* mqa   = (const float*)d_in[9];
  const float* lqa   = (const float*)d_in[10];
  const float* W1    = (const float*)d_in[11];
  const float* b1    = (const float*)d_in[12];
  const float* W2    = (const float*)d_in[13];
  const float* b2    = (const float*)d_in[14];
  const float* Wmt   = (const float*)d_in[15];
  const float* bmt   = (const float*)d_in[16];
  const float* Wlt   = (const float*)d_in[17];
  const float* blt   = (const float*)d_in[18];
  const float* Wem   = (const float*)d_in[19];
  const float* bem   = (const float*)d_in[20];
  const float* Wih   = (const float*)d_in[21];
  const float* Whh   = (const float*)d_in[22];
  const float* bih   = (const float*)d_in[23];
  const float* bhh   = (const float*)d_in[24];
  const float* Wme   = (const float*)d_in[25];
  const float* bme   = (const float*)d_in[26];
  const float* Wle   = (const float*)d_in[27];
  const float* ble   = (const float*)d_in[28];
  float* ws  = (float*)d_ws;
  float* out = (float*)d_out;

  k_zero<<<dim3(201), dim3(256), 0, stream>>>(ws);
  k_alpha<<<dim3(2500), dim3(256), 0, stream>>>(mqa, lqa, eps_a, ws);
  k_eta_gemm<<<dim3(40,25,2), dim3(256), 0, stream>>>(rnn, Wem, ws);
  k_eta_merge<<<dim3(40), dim3(256), 0, stream>>>(ws);

  float* x0  = ws + WS_X0;
  float* x1  = ws + WS_X1;
  float* pre = ws + WS_PRE;
  k_lstm_pre<<<dim3(50), dim3(832), 0, stream>>>(Wih, bih, bhh, bem, x0, pre, 0);
  k_lstm_scan<<<dim3(1), dim3(1024), 0, stream>>>(Whh, pre, x1, 0);
  k_lstm_pre<<<dim3(50), dim3(832), 0, stream>>>(Wih, bih, bhh, (const float*)nullptr, x1, pre, 1);
  k_lstm_scan<<<dim3(1), dim3(1024), 0, stream>>>(Whh, pre, x0, 1);
  k_lstm_pre<<<dim3(50), dim3(832), 0, stream>>>(Wih, bih, bhh, (const float*)nullptr, x0, pre, 2);
  k_lstm_scan<<<dim3(1), dim3(1024), 0, stream>>>(Whh, pre, x1, 2);

  k_eta_chain<<<dim3(1), dim3(256), 0, stream>>>(x1, Wme, bme, Wle, ble, eps_e, ws);
  k_tmask<<<dim3(1), dim3(64), 0, stream>>>(times, ws);

  k_h1_gemm<<<dim3(10,25), dim3(256), 0, stream>>>(nb, W1, ws);
  k_h1_final<<<dim3(200), dim3(256), 0, stream>>>(W1, b1, times, ws);
  k_h2<<<dim3(13,64), dim3(256), 0, stream>>>(W2, b2, ws);
  k_theta<<<dim3(64), dim3(128), 0, stream>>>(Wmt, bmt, Wlt, blt, eps_t, times, ws);

  k_logit_stats<<<dim3(157,40), dim3(256), 0, stream>>>(rho, ws);
  k_stats_merge<<<dim3(313), dim3(256), 0, stream>>>(ws);
  k_lik<<<dim3(313,50), dim3(256), 0, stream>>>(rho, nb, times, ws);

  k_final<<<dim3(1), dim3(64), 0, stream>>>(ws, out);
}

// Round 7
// 3439.668 us; speedup vs baseline: 1.4537x; 1.1814x over previous
//
#include <hip/hip_runtime.h>
#include <math.h>

#define V_ 20000
#define K_ 50
#define T_ 50
#define E_ 300
#define TH_ 800
#define EH_ 200
#define B_ 64

// ---- workspace layout (float offsets) ----
#define WS_SC      0        // [0]=kl_alpha [1]=kl_eta [2]=kl_theta_sum [3]=nll_sum
#define WS_ALPHAS  8        // 750000
#define WS_X0      750008   // 10000
#define WS_X1      760008   // 10000
#define WS_PRE     770008   // 40000
#define WS_ETAS    810008   // 2500
#define WS_H1      812508   // 51200
#define WS_H2      863708   // 51200
#define WS_THETA   914908   // 3200
#define WS_M       918108   // 2500
#define WS_S       920608   // 2500
#define WS_PM      923108   // 157*2500 = 392500
#define WS_PS      1315608  // 392500   -> total 1708108 floats (~6.8 MB)
// eta-map partials alias the PM/PS region (dead until k_logit_stats runs)
#define WS_EPART   WS_PM    // 40*10000 = 400000 floats
// present-t bitmap (ints) aliases WS_PRE (dead after LSTM phase)
#define WS_TPRES   WS_PRE

#define SNB 204   // LDS row stride for h1 gemm tiles
#define VC 512    // eta-map v-chunk
#define SAB 104   // bf16 LDS row stride for MFMA tiles (208B = 13*16B, odd groups)

typedef short short8 __attribute__((ext_vector_type(8)));
typedef float floatx4 __attribute__((ext_vector_type(4)));

__device__ __forceinline__ float sigf(float x){ return 1.0f/(1.0f+expf(-x)); }

// round-to-nearest-even fp32 -> bf16
__device__ __forceinline__ unsigned short f2bf(float f){
  unsigned int u = __float_as_uint(f);
  return (unsigned short)((u + 0x7FFFu + ((u >> 16) & 1u)) >> 16);
}

// ------------------------------------------------------------------
__global__ void k_zero(float* ws){
  int i = blockIdx.x*256 + threadIdx.x;
  if (i < 8) ws[WS_SC + i] = 0.f;
  else if (i < 8 + 51200) ws[WS_H1 + (i-8)] = 0.f;
}

// ---- alphas = mu + eps*exp(0.5 ls); kl_alpha ----
__global__ void __launch_bounds__(256) k_alpha(const float* mu_q, const float* ls_q,
                                               const float* eps, float* ws){
  int bid = blockIdx.x; int t = bid / K_, k = bid % K_;
  int tid = threadIdx.x;
  const float log_delta = logf(0.005f);
  const float pvar = expf(log_delta) + 1e-6f;
  float kl = 0.f;
  for (int e = tid; e < E_; e += 256){
    float mu = mu_q[(k*T_ + t)*E_ + e];
    float ls = ls_q[(k*T_ + t)*E_ + e];
    float ep = eps[(t*K_ + k)*E_ + e];
    float al = mu + ep*expf(0.5f*ls);
    ws[WS_ALPHAS + (t*K_ + k)*E_ + e] = al;
    if (t == 0){
      kl += 0.5f*((expf(ls) + mu*mu)/(1.f + 1e-6f) - 1.f - ls);
    } else {
      float mup = mu_q[(k*T_ + (t-1))*E_ + e];
      float lsp = ls_q[(k*T_ + (t-1))*E_ + e];
      float epp = eps[((t-1)*K_ + k)*E_ + e];
      float ap  = mup + epp*expf(0.5f*lsp);
      float d = mu - ap;
      kl += 0.5f*((expf(ls) + d*d)/pvar - 1.f + log_delta - ls);
    }
  }
  __shared__ float red[256];
  red[tid] = kl; __syncthreads();
  for (int s = 128; s; s >>= 1){ if (tid < s) red[tid] += red[tid+s]; __syncthreads(); }
  if (tid == 0) atomicAdd(&ws[WS_SC + 0], red[0]);
}

// ---- eta_map GEMM: partial[vc][t][h] = rnn[t, v-chunk] . W[h, v-chunk] ----
__global__ void __launch_bounds__(256) k_eta_gemm(const float* rnn, const float* W, float* ws){
  int vc = blockIdx.x;
  int h0 = blockIdx.y * 8;
  int t0 = blockIdx.z * 25;
  int v0 = vc * VC;
  int valid4 = (V_ - v0 >= VC) ? (VC >> 2) : ((V_ - v0) >> 2);
  int tid = threadIdx.x;
  __shared__ __align__(16) float rs[25*VC];
  for (int idx = tid; idx < 25*128; idx += 256){
    int r = idx >> 7, c = idx & 127;
    float4 v = (c < valid4) ? *(const float4*)&rnn[(size_t)(t0 + r)*V_ + v0 + 4*c]
                            : make_float4(0.f,0.f,0.f,0.f);
    *(float4*)&rs[r*VC + 4*c] = v;
  }
  int g = tid >> 5, lane = tid & 31;
  float4 wreg[4];
  #pragma unroll
  for (int i = 0; i < 4; ++i){
    int c4 = lane + 32*i;
    wreg[i] = (c4 < valid4) ? *(const float4*)&W[(size_t)(h0+g)*V_ + v0 + 4*c4]
                            : make_float4(0.f,0.f,0.f,0.f);
  }
  __syncthreads();
  for (int tl = 0; tl < 25; ++tl){
    const float* rrow = rs + tl*VC;
    float s = 0.f;
    #pragma unroll
    for (int i = 0; i < 4; ++i){
      float4 a = *(const float4*)&rrow[4*(lane + 32*i)];
      s += a.x*wreg[i].x + a.y*wreg[i].y + a.z*wreg[i].z + a.w*wreg[i].w;
    }
    #pragma unroll
    for (int m = 16; m; m >>= 1) s += __shfl_xor(s, m, 32);
    if (lane == 0) ws[WS_EPART + vc*(T_*EH_) + (t0 + tl)*EH_ + h0 + g] = s;
  }
}

// ---- merge eta partials -> x0 ----
__global__ void k_eta_merge(float* ws){
  int idx = blockIdx.x*256 + threadIdx.x;
  if (idx >= T_*EH_) return;
  float s = 0.f;
  for (int vc = 0; vc < 40; ++vc) s += ws[WS_EPART + vc*(T_*EH_) + idx];
  ws[WS_X0 + idx] = s;
}

// ---- pre[t,r] = Wih[l] @ x_t + bih + bhh ----
__global__ void __launch_bounds__(832) k_lstm_pre(const float* Wih, const float* bih,
                                                  const float* bhh, const float* emb,
                                                  const float* xin, float* pre, int layer){
  int t = blockIdx.x, tid = threadIdx.x;
  __shared__ __align__(16) float xs[EH_];
  if (tid < EH_) xs[tid] = xin[t*EH_ + tid] + (emb ? emb[tid] : 0.f);
  __syncthreads();
  if (tid < 800){
    const float4* w4 = (const float4*)(Wih + (size_t)layer*160000 + (size_t)tid*200);
    const float4* x4 = (const float4*)xs;
    float a0 = 0.f, a1 = 0.f;
    #pragma unroll 5
    for (int c = 0; c < 50; c += 2){
      float4 w = w4[c],   x = x4[c];
      a0 += w.x*x.x + w.y*x.y + w.z*x.z + w.w*x.w;
      float4 w2 = w4[c+1], x2 = x4[c+1];
      a1 += w2.x*x2.x + w2.y*x2.y + w2.z*x2.z + w2.w*x2.w;
    }
    pre[t*800 + tid] = a0 + a1 + bih[layer*800 + tid] + bhh[layer*800 + tid];
  }
}

// ---- sequential LSTM scan for one layer (validated) ----
__global__ void __launch_bounds__(1024) k_lstm_scan(const float* Whh, const float* pre,
                                                    float* xout, int layer){
  int tid = threadIdx.x;
  __shared__ __align__(16) float hs[EH_];
  __shared__ float cs[EH_];
  __shared__ float gs[800];
  if (tid < EH_){ hs[tid] = 0.f; cs[tid] = 0.f; }
  __syncthreads();
  const float4* w4 = (const float4*)(Whh + (size_t)layer*160000 + (size_t)(tid < 800 ? tid : 0)*200);
  for (int t = 0; t < T_; ++t){
    if (tid < 800){
      const float4* h4 = (const float4*)hs;
      float a0 = 0.f, a1 = 0.f;
      #pragma unroll 5
      for (int c = 0; c < 50; c += 2){
        float4 w = w4[c],   h = h4[c];
        a0 += w.x*h.x + w.y*h.y + w.z*h.z + w.w*h.w;
        float4 w2 = w4[c+1], h2 = h4[c+1];
        a1 += w2.x*h2.x + w2.y*h2.y + w2.z*h2.z + w2.w*h2.w;
      }
      gs[tid] = pre[t*800 + tid] + a0 + a1;
    }
    __syncthreads();
    if (tid < EH_){
      float ig = sigf(gs[tid]);
      float fg = sigf(gs[200+tid]);
      float gg = tanhf(gs[400+tid]);
      float og = sigf(gs[600+tid]);
      float cc = fg*cs[tid] + ig*gg;
      cs[tid] = cc;
      float hh = og*tanhf(cc);
      hs[tid] = hh;
      xout[t*EH_ + tid] = hh;
    }
    __syncthreads();
  }
}

// ---- sequential eta chain: etas (T,K) + kl_eta ----
__global__ void __launch_bounds__(256) k_eta_chain(const float* x, const float* Wmu,
                                                   const float* bmu, const float* Wls,
                                                   const float* bls, const float* eps_eta,
                                                   float* ws){
  int tid = threadIdx.x;
  __shared__ float xs[EH_];
  __shared__ float etap[2][K_];
  __shared__ float kls[K_];
  const float log_delta = logf(0.005f);
  const float pvar = expf(log_delta) + 1e-6f;
  int j = tid >> 2, q = tid & 3;
  float klacc = 0.f;
  for (int t = 0; t < T_; ++t){
    if (tid < EH_) xs[tid] = x[t*EH_ + tid];
    __syncthreads();
    int rb = t & 1, wb = rb ^ 1;
    if (j < K_){
      float pm = 0.f, pl = 0.f;
      for (int c = q; c < 250; c += 4){
        float inp = (c < 200) ? xs[c] : ((t == 0) ? 0.f : etap[rb][c-200]);
        pm += Wmu[j*250 + c]*inp;
        pl += Wls[j*250 + c]*inp;
      }
      pm += __shfl_xor(pm, 1, 4); pm += __shfl_xor(pm, 2, 4);
      pl += __shfl_xor(pl, 1, 4); pl += __shfl_xor(pl, 2, 4);
      if (q == 0){
        float mu = pm + bmu[j], lsv = pl + bls[j];
        float klj;
        if (t == 0){
          klj = 0.5f*((expf(lsv) + mu*mu)/(1.f + 1e-6f) - 1.f - lsv);
        } else {
          float d = mu - etap[rb][j];
          klj = 0.5f*((expf(lsv) + d*d)/pvar - 1.f + log_delta - lsv);
        }
        float eta = mu + eps_eta[t*K_ + j]*expf(0.5f*lsv);
        etap[wb][j] = eta;
        kls[j] = klj;
        ws[WS_ETAS + t*K_ + j] = eta;
      }
    }
    __syncthreads();
    if (tid < 64){
      float v = (tid < K_) ? kls[tid] : 0.f;
      for (int m = 32; m; m >>= 1) v += __shfl_xor(v, m, 64);
      if (tid == 0) klacc += v;
    }
    __syncthreads();
  }
  if (tid == 0) ws[WS_SC + 1] = klacc;
}

// ---- present-t bitmap (into WS_TPRES, dead PRE region) ----
__global__ void k_tmask(const int* times, float* ws){
  int t = threadIdx.x;
  if (t < T_){
    int p = 0;
    for (int b = 0; b < B_; ++b) p |= (times[b] == t) ? 1 : 0;
    ((int*)ws)[WS_TPRES + t] = p;
  }
}

// ---- h1pre[b,r] partial GEMM over the bow (V) part, atomic accumulate ----
__global__ void __launch_bounds__(256) k_h1_gemm(const float* nb, const float* W1, float* ws){
  int v0 = blockIdx.x * 2000;
  int r0 = blockIdx.y * 32;
  int tid = threadIdx.x;
  __shared__ __align__(16) float nbs[64*SNB];
  __shared__ __align__(16) float w1s[32*SNB];
  int dg = tid & 15, rg = tid >> 4;
  float acc[2][4] = {};
  for (int vs = 0; vs < 10; ++vs){
    int vbase = v0 + vs*200;
    __syncthreads();
    for (int idx = tid; idx < 64*50; idx += 256){
      int d = idx / 50, qq = idx % 50;
      float4 val = *(const float4*)&nb[(size_t)d*V_ + vbase + 4*qq];
      *(float4*)&nbs[d*SNB + 4*qq] = val;
    }
    for (int idx = tid; idx < 32*100; idx += 256){
      int r = idx / 100, qq = idx % 100;
      float2 val = *(const float2*)&W1[(size_t)(r0+r)*20050 + vbase + 2*qq];
      *(float2*)&w1s[r*SNB + 2*qq] = val;
    }
    __syncthreads();
    for (int v = 0; v < 200; ++v){
      float a0 = w1s[rg*SNB + v];
      float a1 = w1s[(rg+16)*SNB + v];
      #pragma unroll
      for (int jd = 0; jd < 4; ++jd){
        float bb = nbs[(dg + 16*jd)*SNB + v];
        acc[0][jd] += a0*bb;
        acc[1][jd] += a1*bb;
      }
    }
  }
  #pragma unroll
  for (int ir = 0; ir < 2; ++ir)
    #pragma unroll
    for (int jd = 0; jd < 4; ++jd)
      atomicAdd(&ws[WS_H1 + (dg + 16*jd)*TH_ + r0 + rg + 16*ir], acc[ir][jd]);
}

// ---- h1 = relu(h1pre + W1[:,V:] @ eta_td + b1) ----
__global__ void k_h1_final(const float* W1, const float* b1, const int* times, float* ws){
  int idx = blockIdx.x*256 + threadIdx.x;
  if (idx >= B_*TH_) return;
  int b = idx / TH_, r = idx % TH_;
  const float* et = ws + WS_ETAS + times[b]*K_;
  const float* w  = W1 + (size_t)r*20050 + V_;
  float s = ws[WS_H1 + idx] + b1[r];
  for (int k = 0; k < K_; ++k) s += w[k]*et[k];
  ws[WS_H1 + idx] = fmaxf(s, 0.f);
}

// ---- h2 = relu(h1 @ W2^T + b2) ----
__global__ void __launch_bounds__(256) k_h2(const float* W2, const float* b2, float* ws){
  int r0 = blockIdx.x * 64;
  int b  = blockIdx.y;
  int tid = threadIdx.x;
  __shared__ __align__(16) float h1s[TH_];
  __shared__ float part[4*68];
  for (int i = tid; i < TH_; i += 256) h1s[i] = ws[WS_H1 + b*TH_ + i];
  __syncthreads();
  int rl = tid & 63, p = tid >> 6;
  int r = r0 + rl;
  float acc = 0.f;
  if (r < TH_){
    const float4* w4 = (const float4*)(W2 + (size_t)r*TH_ + p*200);
    const float4* h4 = (const float4*)(h1s + p*200);
    #pragma unroll 5
    for (int c = 0; c < 50; ++c){
      float4 w = w4[c], h = h4[c];
      acc += w.x*h.x + w.y*h.y + w.z*h.z + w.w*h.w;
    }
  }
  part[p*68 + rl] = acc;
  __syncthreads();
  if (tid < 64 && r0 + tid < TH_){
    float s = part[tid] + part[68+tid] + part[136+tid] + part[204+tid] + b2[r0+tid];
    ws[WS_H2 + b*TH_ + r0 + tid] = fmaxf(s, 0.f);
  }
}

// ---- mu_t, ls_t, z, theta(softmax), kl_theta ----
__global__ void __launch_bounds__(128) k_theta(const float* Wmu, const float* bmu,
                                               const float* Wls, const float* bls,
                                               const float* eps_th, const int* times, float* ws){
  int b = blockIdx.x, tid = threadIdx.x;
  __shared__ __align__(16) float h2s[TH_];
  __shared__ float mus[K_], lss[K_];
  for (int i = tid; i < TH_; i += 128) h2s[i] = ws[WS_H2 + b*TH_ + i];
  __syncthreads();
  if (tid < 100){
    int j = (tid < 50) ? tid : tid - 50;
    const float* Wr = (tid < 50) ? (Wmu + j*TH_) : (Wls + j*TH_);
    const float4* w4 = (const float4*)Wr;
    const float4* h4 = (const float4*)h2s;
    float a = 0.f;
    #pragma unroll 5
    for (int c = 0; c < 200; ++c){
      float4 w = w4[c], h = h4[c];
      a += w.x*h.x + w.y*h.y + w.z*h.z + w.w*h.w;
    }
    if (tid < 50) mus[j] = a + bmu[j]; else lss[j] = a + bls[j];
  }
  __syncthreads();
  if (tid < 64){
    int k = tid;
    bool ok = (k < K_);
    float mu  = ok ? mus[k] : 0.f;
    float lsv = ok ? lss[k] : 0.f;
    float etd = ok ? ws[WS_ETAS + times[b]*K_ + k] : 0.f;
    float z   = ok ? (mu + eps_th[b*K_ + k]*expf(0.5f*lsv)) : -1e30f;
    float m = z;
    for (int s = 32; s; s >>= 1) m = fmaxf(m, __shfl_xor(m, s, 64));
    float ez = ok ? expf(z - m) : 0.f;
    float ssum = ez;
    for (int s = 32; s; s >>= 1) ssum += __shfl_xor(ssum, s, 64);
    if (ok) ws[WS_THETA + b*K_ + k] = ez / ssum;
    float d = mu - etd;
    float kl = ok ? 0.5f*((expf(lsv) + d*d)/(1.f + 1e-6f) - 1.f - lsv) : 0.f;
    for (int s = 32; s; s >>= 1) kl += __shfl_xor(kl, s, 64);
    if (tid == 0) atomicAdd(&ws[WS_SC + 2], kl);
  }
}

// ---- pass A (MFMA bf16): logit tile GEMM + per-(row,vchunk) partial max/sumexp ----
// grid (157 col-chunks of 128, 20 row-chunks of 128)
__global__ void __launch_bounds__(256) k_logit_stats(const float* rho, float* ws){
  int ct = blockIdx.x, rt = blockIdx.y;
  int row0 = rt*128, col0 = ct*128;
  {
    const int* pres = (const int*)ws + WS_TPRES;
    int tA = row0 / K_;
    int tB = (row0 + 127) / K_; if (tB > T_-1) tB = T_-1;
    bool need = false;
    for (int tt = tA; tt <= tB; ++tt) need = need || (pres[tt] != 0);
    if (!need) return;
  }
  int tid = threadIdx.x;
  __shared__ __align__(16) unsigned short As[128*SAB];
  __shared__ __align__(16) unsigned short Rs[128*SAB];
  __shared__ float pmw[2][128], psw[2][128];
  int w = tid >> 6, lane = tid & 63;
  int wr = w >> 1, wc = w & 1;
  int l15 = lane & 15, l4 = lane >> 4;

  floatx4 z4 = {0.f, 0.f, 0.f, 0.f};
  floatx4 acc[4][4];
  #pragma unroll
  for (int i = 0; i < 4; ++i)
    #pragma unroll
    for (int j = 0; j < 4; ++j) acc[i][j] = z4;

  for (int ec = 0; ec < 4; ++ec){
    int kbase = ec*96;
    int kvalid = (E_ - kbase < 96) ? (E_ - kbase) : 96;  // 96,96,96,12
    int q4max = kvalid >> 2;
    __syncthreads();
    for (int idx = tid; idx < 128*26; idx += 256){
      int r = idx / 26, q4 = idx % 26;
      int row = row0 + r;
      ushort4 o = {0,0,0,0};
      if (q4 < q4max && row < T_*K_){
        float4 v = *(const float4*)&ws[WS_ALPHAS + (size_t)row*E_ + kbase + 4*q4];
        o.x = f2bf(v.x); o.y = f2bf(v.y); o.z = f2bf(v.z); o.w = f2bf(v.w);
      }
      *(ushort4*)&As[r*SAB + 4*q4] = o;
    }
    for (int idx = tid; idx < 128*26; idx += 256){
      int c = idx / 26, q4 = idx % 26;
      int col = col0 + c;
      ushort4 o = {0,0,0,0};
      if (q4 < q4max && col < V_){
        float4 v = *(const float4*)&rho[(size_t)col*E_ + kbase + 4*q4];
        o.x = f2bf(v.x); o.y = f2bf(v.y); o.z = f2bf(v.z); o.w = f2bf(v.w);
      }
      *(ushort4*)&Rs[c*SAB + 4*q4] = o;
    }
    __syncthreads();
    int ksteps = (kvalid + 31) >> 5;
    for (int ks = 0; ks < ksteps; ++ks){
      int koff = ks*32 + l4*8;
      short8 af[4], bf[4];
      #pragma unroll
      for (int i = 0; i < 4; ++i)
        af[i] = *(const short8*)&As[(wr*64 + i*16 + l15)*SAB + koff];
      #pragma unroll
      for (int j = 0; j < 4; ++j)
        bf[j] = *(const short8*)&Rs[(wc*64 + j*16 + l15)*SAB + koff];
      #pragma unroll
      for (int i = 0; i < 4; ++i)
        #pragma unroll
        for (int j = 0; j < 4; ++j)
          acc[i][j] = __builtin_amdgcn_mfma_f32_16x16x32_bf16(af[i], bf[j], acc[i][j], 0, 0, 0);
    }
  }
  // per-row max & sumexp over this block's 128 cols
  #pragma unroll
  for (int rg = 0; rg < 4; ++rg){
    #pragma unroll
    for (int r = 0; r < 4; ++r){
      float vmax = -1e30f;
      #pragma unroll
      for (int cf = 0; cf < 4; ++cf){
        int col = col0 + wc*64 + cf*16 + l15;
        if (col < V_) vmax = fmaxf(vmax, acc[rg][cf][r]);
      }
      vmax = fmaxf(vmax, __shfl_xor(vmax, 1, 64));
      vmax = fmaxf(vmax, __shfl_xor(vmax, 2, 64));
      vmax = fmaxf(vmax, __shfl_xor(vmax, 4, 64));
      vmax = fmaxf(vmax, __shfl_xor(vmax, 8, 64));
      float sx = 0.f;
      #pragma unroll
      for (int cf = 0; cf < 4; ++cf){
        int col = col0 + wc*64 + cf*16 + l15;
        if (col < V_) sx += expf(acc[rg][cf][r] - vmax);
      }
      sx += __shfl_xor(sx, 1, 64); sx += __shfl_xor(sx, 2, 64);
      sx += __shfl_xor(sx, 4, 64); sx += __shfl_xor(sx, 8, 64);
      if (l15 == 0){
        int rl = wr*64 + rg*16 + l4*4 + r;
        pmw[wc][rl] = vmax; psw[wc][rl] = sx;
      }
    }
  }
  __syncthreads();
  if (tid < 128){
    float m0 = pmw[0][tid], m1 = pmw[1][tid];
    float mm = fmaxf(m0, m1);
    float ss = psw[0][tid]*expf(m0 - mm) + psw[1][tid]*expf(m1 - mm);
    int row = row0 + tid;
    if (row < T_*K_){
      ws[WS_PM + ct*2500 + row] = mm;
      ws[WS_PS + ct*2500 + row] = ss;
    }
  }
}

// ---- merge partial (m,s) over 157 chunks ----
__global__ void k_stats_merge(float* ws){
  int row = blockIdx.x*8 + (threadIdx.x >> 5);
  int lane = threadIdx.x & 31;
  if (row >= T_*K_) return;
  float m = -1e30f;
  for (int i = lane; i < 157; i += 32) m = fmaxf(m, ws[WS_PM + i*2500 + row]);
  for (int s = 16; s; s >>= 1) m = fmaxf(m, __shfl_xor(m, s, 32));
  float ssum = 0.f;
  for (int i = lane; i < 157; i += 32)
    ssum += ws[WS_PS + i*2500 + row]*expf(ws[WS_PM + i*2500 + row] - m);
  for (int s = 16; s; s >>= 1) ssum += __shfl_xor(ssum, s, 32);
  if (lane == 0){ ws[WS_M + row] = m; ws[WS_S + row] = ssum; }
}

// ---- pass B (MFMA bf16): recompute logits for needed t, beta, mixture, NLL ----
// grid (157 col-chunks of 128, 50 t)
__global__ void __launch_bounds__(256) k_lik(const float* rho, const float* nb,
                                             const int* times, float* ws){
  int ct = blockIdx.x, t = blockIdx.y;
  int col0 = ct*128;
  int tid = threadIdx.x;
  __shared__ unsigned long long dmask;
  bool pred = (tid < B_) && (times[tid < B_ ? tid : 0] == t);
  unsigned long long mk = __ballot(pred);
  if (tid == 0) dmask = mk;
  __syncthreads();
  unsigned long long mask = dmask;
  if (mask == 0ull) return;

  __shared__ __align__(16) char smem[64*SAB*2 + 128*SAB*2];  // As(13312) + Rs(26624); P overlays
  __shared__ float Qs[256];
  __shared__ float red2[2];
  unsigned short* As = (unsigned short*)smem;
  unsigned short* Rs = (unsigned short*)(smem + 64*SAB*2);

  int w = tid >> 6, lane = tid & 63;
  int wr = w >> 1, wc = w & 1;
  int l15 = lane & 15, l4 = lane >> 4;

  floatx4 z4 = {0.f, 0.f, 0.f, 0.f};
  floatx4 acc[2][4];
  #pragma unroll
  for (int i = 0; i < 2; ++i)
    #pragma unroll
    for (int j = 0; j < 4; ++j) acc[i][j] = z4;

  for (int ec = 0; ec < 4; ++ec){
    int kbase = ec*96;
    int kvalid = (E_ - kbase < 96) ? (E_ - kbase) : 96;
    int q4max = kvalid >> 2;
    __syncthreads();
    for (int idx = tid; idx < 64*26; idx += 256){
      int r = idx / 26, q4 = idx % 26;
      ushort4 o = {0,0,0,0};
      if (q4 < q4max && r < K_){
        float4 v = *(const float4*)&ws[WS_ALPHAS + (size_t)(t*K_ + r)*E_ + kbase + 4*q4];
        o.x = f2bf(v.x); o.y = f2bf(v.y); o.z = f2bf(v.z); o.w = f2bf(v.w);
      }
      *(ushort4*)&As[r*SAB + 4*q4] = o;
    }
    for (int idx = tid; idx < 128*26; idx += 256){
      int c = idx / 26, q4 = idx % 26;
      int col = col0 + c;
      ushort4 o = {0,0,0,0};
      if (q4 < q4max && col < V_){
        float4 v = *(const float4*)&rho[(size_t)col*E_ + kbase + 4*q4];
        o.x = f2bf(v.x); o.y = f2bf(v.y); o.z = f2bf(v.z); o.w = f2bf(v.w);
      }
      *(ushort4*)&Rs[c*SAB + 4*q4] = o;
    }
    __syncthreads();
    int ksteps = (kvalid + 31) >> 5;
    for (int ks = 0; ks < ksteps; ++ks){
      int koff = ks*32 + l4*8;
      short8 af[2], bf[4];
      #pragma unroll
      for (int i = 0; i < 2; ++i)
        af[i] = *(const short8*)&As[(wr*32 + i*16 + l15)*SAB + koff];
      #pragma unroll
      for (int j = 0; j < 4; ++j)
        bf[j] = *(const short8*)&Rs[(wc*64 + j*16 + l15)*SAB + koff];
      #pragma unroll
      for (int i = 0; i < 2; ++i)
        #pragma unroll
        for (int j = 0; j < 4; ++j)
          acc[i][j] = __builtin_amdgcn_mfma_f32_16x16x32_bf16(af[i], bf[j], acc[i][j], 0, 0, 0);
    }
  }
  // form beta rows into P (overlays As/Rs)
  __syncthreads();
  float* P = (float*)smem;   // [50][136]
  #pragma unroll
  for (int rg = 0; rg < 2; ++rg){
    #pragma unroll
    for (int r = 0; r < 4; ++r){
      int rl = wr*32 + rg*16 + l4*4 + r;
      if (rl < K_){
        float mm = ws[WS_M + t*K_ + rl];
        float si = 1.f / ws[WS_S + t*K_ + rl];
        #pragma unroll
        for (int cf = 0; cf < 4; ++cf){
          int cl = wc*64 + cf*16 + l15;
          if (col0 + cl < V_) P[rl*136 + cl] = expf(acc[rg][cf][r] - mm)*si;
        }
      }
    }
  }
  __syncthreads();
  // mixture + NLL per masked doc
  float nllloc = 0.f;
  int cl = tid & 127, kk = tid >> 7;
  for (unsigned long long m2 = mask; m2; m2 &= (m2-1)){
    int b = __ffsll((long long)m2) - 1;
    float partial = 0.f;
    #pragma unroll
    for (int k = 0; k < 25; ++k)
      partial += ws[WS_THETA + b*K_ + kk*25 + k] * P[(kk*25 + k)*136 + cl];
    Qs[kk*128 + cl] = partial;
    __syncthreads();
    if (tid < 128){
      float q = Qs[tid] + Qs[128 + tid];
      int col = col0 + tid;
      float term = (col < V_) ? (-logf(q + 1e-6f)*nb[(size_t)b*V_ + col]) : 0.f;
      #pragma unroll
      for (int s2 = 32; s2; s2 >>= 1) term += __shfl_xor(term, s2, 64);
      if ((tid & 63) == 0) red2[tid >> 6] = term;
    }
    __syncthreads();
    if (tid == 0) nllloc += red2[0] + red2[1];
    __syncthreads();
  }
  if (tid == 0) atomicAdd(&ws[WS_SC + 3], nllloc);
}

// ---- assemble outputs ----
__global__ void k_final(const float* ws, float* out){
  if (threadIdx.x == 0 && blockIdx.x == 0){
    float nll = ws[WS_SC+3] / (float)B_;
    float kla = ws[WS_SC+0];
    float kle = ws[WS_SC+1];
    float klt = ws[WS_SC+2] / (float)B_;
    out[0] = nll + kla + kle + klt;
    out[1] = nll;
    out[2] = kla;
    out[3] = kle;
    out[4] = klt;
  }
}

// ------------------------------------------------------------------
extern "C" void kernel_launch(void* const* d_in, const int* in_sizes, int n_in,
                              void* d_out, int out_size, void* d_ws, size_t ws_size,
                              hipStream_t stream){
  const float* nb    = (const float*)d_in[1];
  const int*   times = (const int*)d_in[2];
  const float* rnn   = (const float*)d_in[3];
  const float* eps_a = (const float*)d_in[5];
  const float* eps_e = (const float*)d_in[6];
  const float* eps_t = (const float*)d_in[7];
  const float* rho   = (const float*)d_in[8];
  const float* mqa   = (const float*)d_in[9];
  const float* lqa   = (const float*)d_in[10];
  const float* W1    = (const float*)d_in[11];
  const float* b1    = (const float*)d_in[12];
  const float* W2    = (const float*)d_in[13];
  const float* b2    = (const float*)d_in[14];
  const float* Wmt   = (const float*)d_in[15];
  const float* bmt   = (const float*)d_in[16];
  const float* Wlt   = (const float*)d_in[17];
  const float* blt   = (const float*)d_in[18];
  const float* Wem   = (const float*)d_in[19];
  const float* bem   = (const float*)d_in[20];
  const float* Wih   = (const float*)d_in[21];
  const float* Whh   = (const float*)d_in[22];
  const float* bih   = (const float*)d_in[23];
  const float* bhh   = (const float*)d_in[24];
  const float* Wme   = (const float*)d_in[25];
  const float* bme   = (const float*)d_in[26];
  const float* Wle   = (const float*)d_in[27];
  const float* ble   = (const float*)d_in[28];
  float* ws  = (float*)d_ws;
  float* out = (float*)d_out;

  k_zero<<<dim3(201), dim3(256), 0, stream>>>(ws);
  k_alpha<<<dim3(2500), dim3(256), 0, stream>>>(mqa, lqa, eps_a, ws);
  k_eta_gemm<<<dim3(40,25,2), dim3(256), 0, stream>>>(rnn, Wem, ws);
  k_eta_merge<<<dim3(40), dim3(256), 0, stream>>>(ws);

  float* x0  = ws + WS_X0;
  float* x1  = ws + WS_X1;
  float* pre = ws + WS_PRE;
  k_lstm_pre<<<dim3(50), dim3(832), 0, stream>>>(Wih, bih, bhh, bem, x0, pre, 0);
  k_lstm_scan<<<dim3(1), dim3(1024), 0, stream>>>(Whh, pre, x1, 0);
  k_lstm_pre<<<dim3(50), dim3(832), 0, stream>>>(Wih, bih, bhh, (const float*)nullptr, x1, pre, 1);
  k_lstm_scan<<<dim3(1), dim3(1024), 0, stream>>>(Whh, pre, x0, 1);
  k_lstm_pre<<<dim3(50), dim3(832), 0, stream>>>(Wih, bih, bhh, (const float*)nullptr, x0, pre, 2);
  k_lstm_scan<<<dim3(1), dim3(1024), 0, stream>>>(Whh, pre, x1, 2);

  k_eta_chain<<<dim3(1), dim3(256), 0, stream>>>(x1, Wme, bme, Wle, ble, eps_e, ws);
  k_tmask<<<dim3(1), dim3(64), 0, stream>>>(times, ws);

  k_h1_gemm<<<dim3(10,25), dim3(256), 0, stream>>>(nb, W1, ws);
  k_h1_final<<<dim3(200), dim3(256), 0, stream>>>(W1, b1, times, ws);
  k_h2<<<dim3(13,64), dim3(256), 0, stream>>>(W2, b2, ws);
  k_theta<<<dim3(64), dim3(128), 0, stream>>>(Wmt, bmt, Wlt, blt, eps_t, times, ws);

  k_logit_stats<<<dim3(157,20), dim3(256), 0, stream>>>(rho, ws);
  k_stats_merge<<<dim3(313), dim3(256), 0, stream>>>(ws);
  k_lik<<<dim3(157,50), dim3(256), 0, stream>>>(rho, nb, times, ws);

  k_final<<<dim3(1), dim3(64), 0, stream>>>(ws, out);
}